// Round 9
// baseline (567.080 us; speedup 1.0000x reference)
//
#include <hip/hip_runtime.h>

#define DIM 1024
#define NROWS 65536
#define PICK 12

// -------------------------------------------------------------------------
// ws layout (floats):
//   0      NK  [12][1024]
//   12288  Qr  [12][1024]
//   24576  Mt  [12][1024]   (zeroed, atomic-accumulated, TRANSPOSED: [j][e])
//   36864  Rt  [12][1024]   (zeroed, atomic-accumulated, TRANSPOSED: [j][e])
//   49152  c0  [12] (pad16, zeroed)
//   49168  c1  [12] (pad16, zeroed)
//   49184  cand_v [768]
//   49952  cand_i [768] (int)
//   50720  top_idx [12] (int, pad16)
//   50736  maxv [65536]
// -------------------------------------------------------------------------

// out[j][d] = sum_e emb[idx[j]][e] * W[d][e] + b[d]      (12 x 1024)
__global__ void __launch_bounds__(256)
rows12_kernel(const float* __restrict__ emb, const float* __restrict__ W,
              const float* __restrict__ b, const int* __restrict__ idx,
              float* __restrict__ out) {
    int d = blockIdx.x;
    int t = threadIdx.x;
    int lane = t & 63;
    int q = t >> 6;
    int e0 = q * 256 + lane * 4;
    float4 w4 = *(const float4*)&W[(size_t)d * DIM + e0];
    float part[PICK];
#pragma unroll
    for (int j = 0; j < PICK; ++j) {
        int r = idx[j];
        float4 e4 = *(const float4*)&emb[(size_t)r * DIM + e0];
        part[j] = w4.x * e4.x + w4.y * e4.y + w4.z * e4.z + w4.w * e4.w;
    }
#pragma unroll
    for (int j = 0; j < PICK; ++j) {
        float v = part[j];
        for (int s = 32; s > 0; s >>= 1) v += __shfl_down(v, s, 64);
        part[j] = v;
    }
    __shared__ float red[4][PICK];
    if (lane == 0) {
#pragma unroll
        for (int j = 0; j < PICK; ++j) red[q][j] = part[j];
    }
    __syncthreads();
    if (t < PICK) {
        float s = red[0][t] + red[1][t] + red[2][t] + red[3][t] + b[d];
        out[t * DIM + d] = s;
    }
}

// TRANSPOSED output: out[j][e] += sum_d W[d][e] * V[j][d];  cvec[j] += sum_d b[d]*V[j][d]
__global__ void __launch_bounds__(256)
colmat_kernel(const float* __restrict__ W, const float* __restrict__ V,
              const float* __restrict__ b, float* __restrict__ out,
              float* __restrict__ cvec) {
    int blk = blockIdx.x;
    int t = threadIdx.x;
    if (blk == 128) {
        float part[PICK];
#pragma unroll
        for (int j = 0; j < PICK; ++j) part[j] = 0.f;
        for (int k = 0; k < 4; ++k) {
            int d = t + k * 256;
            float bv = b[d];
#pragma unroll
            for (int j = 0; j < PICK; ++j) part[j] += bv * V[j * DIM + d];
        }
#pragma unroll
        for (int j = 0; j < PICK; ++j) {
            float v = part[j];
            for (int s = 32; s > 0; s >>= 1) v += __shfl_down(v, s, 64);
            if ((t & 63) == 0) atomicAdd(&cvec[j], v);
        }
        return;
    }
    int eg = blk & 3;
    int dg = blk >> 2;
    int e = eg * 256 + t;
    int d0 = dg * 32;
    __shared__ float Vs[PICK][32];
    for (int i = t; i < PICK * 32; i += 256) {
        int j = i >> 5, dd = i & 31;
        Vs[j][dd] = V[j * DIM + d0 + dd];
    }
    __syncthreads();
    float acc[PICK];
#pragma unroll
    for (int j = 0; j < PICK; ++j) acc[j] = 0.f;
    for (int dd = 0; dd < 32; ++dd) {
        float w = W[(size_t)(d0 + dd) * DIM + e];
#pragma unroll
        for (int j = 0; j < PICK; ++j) acc[j] += w * Vs[j][dd];
    }
#pragma unroll
    for (int j = 0; j < PICK; ++j) atomicAdd(&out[j * DIM + e], acc[j]);
}

// -------------------------------------------------------------------------
// pass kernels (R14): 8-row tile WITHOUT the register cap.
// R13 post-mortem (6th null): no single pipe saturates, but the JOINT
// budget vs the 98K-cyc/CU HBM window is DS 56% + VALU-issue 38% + VMEM
// ~20% -> combined contention pins the passes at ~2x the HBM floor
// (~2.7 TB/s, R5's spill-corrected rate). The only lever that REMOVES
// work (instead of moving it between pipes) is m-read amortization:
// 8 rows per m-load -> DS 56% -> 19%.
// R4 tried 8-row and spilled -- but that was the __launch_bounds__(256,2)
// 128-VGPR cap, not the idea (R6 proved no-attr doesn't spill).
// Budget: acc[8][12]=96 + ping-pong bufs 64 + m-quarter 12 + addr ~20
// ~= 195 VGPR < 256 -> 2 waves/SIMD, 8 waves/CU, no spill.
// Epilogue stays pure-VALU DPP (R13). Prefetch in-flight ~80 KB/CU vs
// ~13 KB needed at loaded latency.
// -------------------------------------------------------------------------

__device__ __forceinline__ float wave_sum64(float v) {
    // inclusive: after this, lane 63 holds the 64-lane total
    v += __int_as_float(__builtin_amdgcn_update_dpp(
        0, __float_as_int(v), 0x111, 0xF, 0xF, true));   // row_shr:1
    v += __int_as_float(__builtin_amdgcn_update_dpp(
        0, __float_as_int(v), 0x112, 0xF, 0xF, true));   // row_shr:2
    v += __int_as_float(__builtin_amdgcn_update_dpp(
        0, __float_as_int(v), 0x114, 0xF, 0xF, true));   // row_shr:4
    v += __int_as_float(__builtin_amdgcn_update_dpp(
        0, __float_as_int(v), 0x118, 0xF, 0xF, true));   // row_shr:8
    v += __int_as_float(__builtin_amdgcn_update_dpp(
        0, __float_as_int(v), 0x142, 0xF, 0xF, true));   // row_bcast:15
    v += __int_as_float(__builtin_amdgcn_update_dpp(
        0, __float_as_int(v), 0x143, 0xF, 0xF, true));   // row_bcast:31
    return v;
}

// one 256-col chunk for 8 rows: prefetch chunk PF_CHUNK of rows PF_ROW..
// into NBUF (8x1KB wave-contiguous), m fragments in quarters of 3 j's
// (12 VGPRs live), FMA CBUF into acc[8][12]
#define CHUNK8(CBUF, NBUF, CC, PF_ROW, PF_CHUNK)                              \
  {                                                                           \
    _Pragma("unroll") for (int r = 0; r < 8; ++r)                             \
      NBUF[r] = *(const float4*)(emb + (size_t)((PF_ROW) + r) * DIM +         \
                                 (PF_CHUNK) * 256 + l * 4);                   \
    _Pragma("unroll") for (int jq = 0; jq < 4; ++jq) {                        \
      float4 m0 = *(const float4*)&sMt[(3 * jq + 0) * DIM + (CC) * 256 + l * 4]; \
      float4 m1 = *(const float4*)&sMt[(3 * jq + 1) * DIM + (CC) * 256 + l * 4]; \
      float4 m2 = *(const float4*)&sMt[(3 * jq + 2) * DIM + (CC) * 256 + l * 4]; \
      _Pragma("unroll") for (int r = 0; r < 8; ++r) {                         \
        float4 vv = CBUF[r];                                                  \
        acc[r][3 * jq + 0] += vv.x * m0.x + vv.y * m0.y + vv.z * m0.z +       \
                              vv.w * m0.w;                                    \
        acc[r][3 * jq + 1] += vv.x * m1.x + vv.y * m1.y + vv.z * m1.z +       \
                              vv.w * m1.w;                                    \
        acc[r][3 * jq + 2] += vv.x * m2.x + vv.y * m2.y + vv.z * m2.z +       \
                              vv.w * m2.w;                                    \
      }                                                                       \
    }                                                                         \
  }

// epilogue for all 8 rows of the tile: 96 independent DPP wave-reductions,
// per-row max over j (+ uniform bias), lane 63 stores the row max.
#define EPI8(SINKBASE)                                                        \
  {                                                                           \
    _Pragma("unroll") for (int r = 0; r < 8; ++r) {                           \
      float vmax = -3e38f;                                                    \
      _Pragma("unroll") for (int j = 0; j < PICK; ++j)                        \
        vmax = fmaxf(vmax, wave_sum64(acc[r][j]) + cb[j]);                    \
      if (l == 63) (SINKBASE)[r] = vmax;                                      \
    }                                                                         \
  }

__global__ void __launch_bounds__(256)
pass1_kernel(const float* __restrict__ emb, const float* __restrict__ Mt,
             const float* __restrict__ c0, float* __restrict__ maxv) {
    __shared__ __align__(16) float sMt[PICK * DIM];        // 48 KB (only LDS)
    int t = threadIdx.x;
    for (int i = t; i < PICK * DIM / 4; i += 256)
        ((float4*)sMt)[i] = ((const float4*)Mt)[i];
    __syncthreads();

    int l = t & 63, w = t >> 6;
    float cb[PICK];
#pragma unroll
    for (int j = 0; j < PICK; ++j) cb[j] = c0[j];   // uniform -> scalar loads
    size_t wrow = (size_t)blockIdx.x * 128 + (size_t)w * 32;

    float4 bufA[8], bufB[8];
#pragma unroll
    for (int r = 0; r < 8; ++r)
        bufA[r] = *(const float4*)(emb + (wrow + r) * DIM + l * 4);

    for (int tile = 0; tile < 4; ++tile) {
        size_t trow = wrow + (size_t)tile * 8;
        size_t ntrow = wrow + (size_t)((tile < 3) ? tile + 1 : 3) * 8;
        float acc[8][PICK];
#pragma unroll
        for (int r = 0; r < 8; ++r)
#pragma unroll
            for (int j = 0; j < PICK; ++j) acc[r][j] = 0.f;

        CHUNK8(bufA, bufB, 0, trow, 1);
        CHUNK8(bufB, bufA, 1, trow, 2);
        CHUNK8(bufA, bufB, 2, trow, 3);
        CHUNK8(bufB, bufA, 3, ntrow, 0);

        EPI8(&maxv[trow]);
    }
}

__global__ void __launch_bounds__(256)
pass2_kernel(const float* __restrict__ emb, const float* __restrict__ Rt,
             const float* __restrict__ c1, float* __restrict__ out) {
    __shared__ __align__(16) float sMt[PICK * DIM];        // 48 KB
    __shared__ float pooled[128];
    int t = threadIdx.x;
    for (int i = t; i < PICK * DIM / 4; i += 256)
        ((float4*)sMt)[i] = ((const float4*)Rt)[i];
    __syncthreads();

    int l = t & 63, w = t >> 6;
    float cb[PICK];
#pragma unroll
    for (int j = 0; j < PICK; ++j) cb[j] = c1[j];
    size_t bbase = (size_t)blockIdx.x * 128;
    size_t wrow = bbase + (size_t)w * 32;

    float4 bufA[8], bufB[8];
#pragma unroll
    for (int r = 0; r < 8; ++r)
        bufA[r] = *(const float4*)(emb + (wrow + r) * DIM + l * 4);

    for (int tile = 0; tile < 4; ++tile) {
        size_t trow = wrow + (size_t)tile * 8;
        size_t ntrow = wrow + (size_t)((tile < 3) ? tile + 1 : 3) * 8;
        float acc[8][PICK];
#pragma unroll
        for (int r = 0; r < 8; ++r)
#pragma unroll
            for (int j = 0; j < PICK; ++j) acc[r][j] = 0.f;

        CHUNK8(bufA, bufB, 0, trow, 1);
        CHUNK8(bufB, bufA, 1, trow, 2);
        CHUNK8(bufA, bufB, 2, trow, 3);
        CHUNK8(bufB, bufA, 3, ntrow, 0);

        EPI8(&pooled[w * 32 + tile * 8]);
    }
    __syncthreads();

    // phase B: thread t owns cols t*4..t*4+3; wave reads are 1 KB contiguous.
    // Re-walk the block's 128 rows (L2/L3-hot from phase A).
    const float* tp = emb + bbase * DIM + t * 4;
    float4 o = {0.f, 0.f, 0.f, 0.f};
#pragma unroll 8
    for (int r = 0; r < 128; ++r) {
        float pv = pooled[r];
        float4 v = *(const float4*)(tp + (size_t)r * DIM);
        o.x += pv * v.x; o.y += pv * v.y; o.z += pv * v.z; o.w += pv * v.w;
    }
    atomicAdd(&out[t * 4 + 0], o.x);
    atomicAdd(&out[t * 4 + 1], o.y);
    atomicAdd(&out[t * 4 + 2], o.z);
    atomicAdd(&out[t * 4 + 3], o.w);
}

// local top-12 of each 1024-chunk of maxv, single wave, register-resident,
// barrier-free: element q*64+t is only ever scanned AND cleared by lane t.
__global__ void __launch_bounds__(64)
top12_local(const float* __restrict__ maxv, float* __restrict__ cand_v,
            int* __restrict__ cand_i) {
    int t = threadIdx.x;
    int base = blockIdx.x * 1024;
    float lv[16];
#pragma unroll
    for (int q = 0; q < 16; ++q) lv[q] = maxv[base + q * 64 + t];
    for (int k = 0; k < PICK; ++k) {
        float bv = -3e38f; int bi = 0x7fffffff;
#pragma unroll
        for (int q = 0; q < 16; ++q) {
            int ii = base + q * 64 + t;
            float v = lv[q];
            if (v > bv || (v == bv && ii < bi)) { bv = v; bi = ii; }
        }
#pragma unroll
        for (int sft = 1; sft < 64; sft <<= 1) {
            float ov = __shfl_xor(bv, sft, 64);
            int oi = __shfl_xor(bi, sft, 64);
            if (ov > bv || (ov == bv && oi < bi)) { bv = ov; bi = oi; }
        }
        if (t == 0) {
            cand_v[blockIdx.x * PICK + k] = bv;
            cand_i[blockIdx.x * PICK + k] = bi;
        }
#pragma unroll
        for (int q = 0; q < 16; ++q)
            if (base + q * 64 + t == bi) lv[q] = -3e38f;
    }
}

// merge 768 candidates -> global top-12 indices; single wave, 12 regs/lane.
__global__ void __launch_bounds__(64)
top12_merge(const float* __restrict__ cand_v, const int* __restrict__ cand_i,
            int* __restrict__ top_idx) {
    int t = threadIdx.x;
    float lv[12]; int li[12];
#pragma unroll
    for (int q = 0; q < 12; ++q) {
        lv[q] = cand_v[q * 64 + t];
        li[q] = cand_i[q * 64 + t];
    }
    for (int k = 0; k < PICK; ++k) {
        float bv = -3e38f; int bi = 0x7fffffff; int bs = -1;
#pragma unroll
        for (int q = 0; q < 12; ++q) {
            if (lv[q] > bv || (lv[q] == bv && li[q] < bi)) {
                bv = lv[q]; bi = li[q]; bs = q * 64 + t;
            }
        }
#pragma unroll
        for (int sft = 1; sft < 64; sft <<= 1) {
            float ov = __shfl_xor(bv, sft, 64);
            int oi = __shfl_xor(bi, sft, 64);
            int os = __shfl_xor(bs, sft, 64);
            if (ov > bv || (ov == bv && oi < bi)) { bv = ov; bi = oi; bs = os; }
        }
        if (t == 0) top_idx[k] = bi;
#pragma unroll
        for (int q = 0; q < 12; ++q)
            if (q * 64 + t == bs) lv[q] = -3e38f;
    }
}

extern "C" void kernel_launch(void* const* d_in, const int* in_sizes, int n_in,
                              void* d_out, int out_size, void* d_ws, size_t ws_size,
                              hipStream_t stream) {
    const float* emb = (const float*)d_in[0];
    const float* Wq  = (const float*)d_in[1];
    const float* bq  = (const float*)d_in[2];
    const float* Wk  = (const float*)d_in[3];
    const float* bk  = (const float*)d_in[4];
    const int* indices = (const int*)d_in[5];
    float* out = (float*)d_out;
    float* ws = (float*)d_ws;

    float* NK      = ws;             // 12288
    float* Qr      = ws + 12288;     // 12288
    float* Mt      = ws + 24576;     // 12288 (zeroed, transposed [12][1024])
    float* Rt      = ws + 36864;     // 12288 (zeroed, transposed [12][1024])
    float* c0      = ws + 49152;     // 16    (zeroed)
    float* c1      = ws + 49168;     // 16    (zeroed)
    float* cand_v  = ws + 49184;     // 768
    int*   cand_i  = (int*)(ws + 49952);   // 768
    int*   top_idx = (int*)(ws + 50720);   // 16
    float* maxv    = ws + 50736;     // 65536

    hipMemsetAsync(Mt, 0, (size_t)(12288 * 2 + 32) * sizeof(float), stream);
    hipMemsetAsync(out, 0, DIM * sizeof(float), stream);

    rows12_kernel<<<1024, 256, 0, stream>>>(emb, Wk, bk, indices, NK);
    colmat_kernel<<<129, 256, 0, stream>>>(Wq, NK, bq, Mt, c0);
    pass1_kernel<<<512, 256, 0, stream>>>(emb, Mt, c0, maxv);
    top12_local<<<64, 64, 0, stream>>>(maxv, cand_v, cand_i);
    top12_merge<<<1, 64, 0, stream>>>(cand_v, cand_i, top_idx);
    rows12_kernel<<<1024, 256, 0, stream>>>(emb, Wq, bq, top_idx, Qr);
    colmat_kernel<<<129, 256, 0, stream>>>(Wk, Qr, bk, Rt, c1);
    pass2_kernel<<<512, 256, 0, stream>>>(emb, Rt, c1, out);
}

// Round 10
// 560.357 us; speedup vs baseline: 1.0120x; 1.0120x over previous
//
#include <hip/hip_runtime.h>

#define DIM 1024
#define NROWS 65536
#define PICK 12

// -------------------------------------------------------------------------
// ws layout (floats):
//   0      NK  [12][1024]
//   12288  Qr  [12][1024]
//   24576  Mt  [12][1024]   (zeroed by rows12#1, atomic-accum, [j][e])
//   36864  Rt  [12][1024]   (zeroed by rows12#1, atomic-accum, [j][e])
//   49152  c0  [12] (pad16, zeroed by rows12#1)
//   49168  c1  [12] (pad16, zeroed by rows12#1)
//   49184  cand_v [768]
//   49952  cand_i [768] (int)
//   50720  top_idx [12] (int, pad16)
//   50736  maxv [65536]
// -------------------------------------------------------------------------
// R15: dispatch-count experiment. 7 structurally different pass kernels all
// landed 555-567 us -> pass internals are not the controlling variable.
// Two accounts fit all data: (a) passes ~105us each (latency floor), or
// (b) passes ~65us + ~10us launch gap x 10 dispatches. This round removes
// the 2 memset dispatches (zeroing folded into rows12#1, which runs before
// any consumer; re-zeroed every iteration so re-poison semantics hold).
// ~540 -> gaps real, pursue kernel fusion; ~560 -> declare roofline.
// -------------------------------------------------------------------------

// out[j][d] = sum_e emb[idx[j]][e] * W[d][e] + b[d]      (12 x 1024)
// zero_base != nullptr (first instance only): blocks 0..24 zero the
// Mt/Rt/c0/c1 region (24608 floats at ws+24576), block 25 zeros outv[1024].
__global__ void __launch_bounds__(256)
rows12_kernel(const float* __restrict__ emb, const float* __restrict__ W,
              const float* __restrict__ b, const int* __restrict__ idx,
              float* __restrict__ out, float* __restrict__ zero_base,
              float* __restrict__ outv) {
    int d = blockIdx.x;
    int t = threadIdx.x;
    if (zero_base) {
        if (d < 25) {
            int i = d * 256 + t;               // float4 index into 24608 floats
            if (i < 6152) ((float4*)zero_base)[i] = make_float4(0.f, 0.f, 0.f, 0.f);
        } else if (d == 25) {
            ((float4*)outv)[t] = make_float4(0.f, 0.f, 0.f, 0.f);
        }
    }
    int lane = t & 63;
    int q = t >> 6;
    int e0 = q * 256 + lane * 4;
    float4 w4 = *(const float4*)&W[(size_t)d * DIM + e0];
    float part[PICK];
#pragma unroll
    for (int j = 0; j < PICK; ++j) {
        int r = idx[j];
        float4 e4 = *(const float4*)&emb[(size_t)r * DIM + e0];
        part[j] = w4.x * e4.x + w4.y * e4.y + w4.z * e4.z + w4.w * e4.w;
    }
#pragma unroll
    for (int j = 0; j < PICK; ++j) {
        float v = part[j];
        for (int s = 32; s > 0; s >>= 1) v += __shfl_down(v, s, 64);
        part[j] = v;
    }
    __shared__ float red[4][PICK];
    if (lane == 0) {
#pragma unroll
        for (int j = 0; j < PICK; ++j) red[q][j] = part[j];
    }
    __syncthreads();
    if (t < PICK) {
        float s = red[0][t] + red[1][t] + red[2][t] + red[3][t] + b[d];
        out[t * DIM + d] = s;
    }
}

// TRANSPOSED output: out[j][e] += sum_d W[d][e] * V[j][d];  cvec[j] += sum_d b[d]*V[j][d]
__global__ void __launch_bounds__(256)
colmat_kernel(const float* __restrict__ W, const float* __restrict__ V,
              const float* __restrict__ b, float* __restrict__ out,
              float* __restrict__ cvec) {
    int blk = blockIdx.x;
    int t = threadIdx.x;
    if (blk == 128) {
        float part[PICK];
#pragma unroll
        for (int j = 0; j < PICK; ++j) part[j] = 0.f;
        for (int k = 0; k < 4; ++k) {
            int d = t + k * 256;
            float bv = b[d];
#pragma unroll
            for (int j = 0; j < PICK; ++j) part[j] += bv * V[j * DIM + d];
        }
#pragma unroll
        for (int j = 0; j < PICK; ++j) {
            float v = part[j];
            for (int s = 32; s > 0; s >>= 1) v += __shfl_down(v, s, 64);
            if ((t & 63) == 0) atomicAdd(&cvec[j], v);
        }
        return;
    }
    int eg = blk & 3;
    int dg = blk >> 2;
    int e = eg * 256 + t;
    int d0 = dg * 32;
    __shared__ float Vs[PICK][32];
    for (int i = t; i < PICK * 32; i += 256) {
        int j = i >> 5, dd = i & 31;
        Vs[j][dd] = V[j * DIM + d0 + dd];
    }
    __syncthreads();
    float acc[PICK];
#pragma unroll
    for (int j = 0; j < PICK; ++j) acc[j] = 0.f;
    for (int dd = 0; dd < 32; ++dd) {
        float w = W[(size_t)(d0 + dd) * DIM + e];
#pragma unroll
        for (int j = 0; j < PICK; ++j) acc[j] += w * Vs[j][dd];
    }
#pragma unroll
    for (int j = 0; j < PICK; ++j) atomicAdd(&out[j * DIM + e], acc[j]);
}

__device__ __forceinline__ float wave_sum64(float v) {
    // inclusive: after this, lane 63 holds the 64-lane total
    v += __int_as_float(__builtin_amdgcn_update_dpp(
        0, __float_as_int(v), 0x111, 0xF, 0xF, true));   // row_shr:1
    v += __int_as_float(__builtin_amdgcn_update_dpp(
        0, __float_as_int(v), 0x112, 0xF, 0xF, true));   // row_shr:2
    v += __int_as_float(__builtin_amdgcn_update_dpp(
        0, __float_as_int(v), 0x114, 0xF, 0xF, true));   // row_shr:4
    v += __int_as_float(__builtin_amdgcn_update_dpp(
        0, __float_as_int(v), 0x118, 0xF, 0xF, true));   // row_shr:8
    v += __int_as_float(__builtin_amdgcn_update_dpp(
        0, __float_as_int(v), 0x142, 0xF, 0xF, true));   // row_bcast:15
    v += __int_as_float(__builtin_amdgcn_update_dpp(
        0, __float_as_int(v), 0x143, 0xF, 0xF, true));   // row_bcast:31
    return v;
}

// one 256-col chunk for 8 rows: prefetch chunk PF_CHUNK of rows PF_ROW..
// into NBUF (8x1KB wave-contiguous), m fragments in quarters of 3 j's,
// FMA CBUF into acc[8][12]
#define CHUNK8(CBUF, NBUF, CC, PF_ROW, PF_CHUNK)                              \
  {                                                                           \
    _Pragma("unroll") for (int r = 0; r < 8; ++r)                             \
      NBUF[r] = *(const float4*)(emb + (size_t)((PF_ROW) + r) * DIM +         \
                                 (PF_CHUNK) * 256 + l * 4);                   \
    _Pragma("unroll") for (int jq = 0; jq < 4; ++jq) {                        \
      float4 m0 = *(const float4*)&sMt[(3 * jq + 0) * DIM + (CC) * 256 + l * 4]; \
      float4 m1 = *(const float4*)&sMt[(3 * jq + 1) * DIM + (CC) * 256 + l * 4]; \
      float4 m2 = *(const float4*)&sMt[(3 * jq + 2) * DIM + (CC) * 256 + l * 4]; \
      _Pragma("unroll") for (int r = 0; r < 8; ++r) {                         \
        float4 vv = CBUF[r];                                                  \
        acc[r][3 * jq + 0] += vv.x * m0.x + vv.y * m0.y + vv.z * m0.z +       \
                              vv.w * m0.w;                                    \
        acc[r][3 * jq + 1] += vv.x * m1.x + vv.y * m1.y + vv.z * m1.z +       \
                              vv.w * m1.w;                                    \
        acc[r][3 * jq + 2] += vv.x * m2.x + vv.y * m2.y + vv.z * m2.z +       \
                              vv.w * m2.w;                                    \
      }                                                                       \
    }                                                                         \
  }

// epilogue for all 8 rows of the tile: 96 independent DPP wave-reductions,
// per-row max over j (+ uniform bias), lane 63 stores the row max.
#define EPI8(SINKBASE)                                                        \
  {                                                                           \
    _Pragma("unroll") for (int r = 0; r < 8; ++r) {                           \
      float vmax = -3e38f;                                                    \
      _Pragma("unroll") for (int j = 0; j < PICK; ++j)                        \
        vmax = fmaxf(vmax, wave_sum64(acc[r][j]) + cb[j]);                    \
      if (l == 63) (SINKBASE)[r] = vmax;                                      \
    }                                                                         \
  }

__global__ void __launch_bounds__(256)
pass1_kernel(const float* __restrict__ emb, const float* __restrict__ Mt,
             const float* __restrict__ c0, float* __restrict__ maxv) {
    __shared__ __align__(16) float sMt[PICK * DIM];        // 48 KB (only LDS)
    int t = threadIdx.x;
    for (int i = t; i < PICK * DIM / 4; i += 256)
        ((float4*)sMt)[i] = ((const float4*)Mt)[i];
    __syncthreads();

    int l = t & 63, w = t >> 6;
    float cb[PICK];
#pragma unroll
    for (int j = 0; j < PICK; ++j) cb[j] = c0[j];   // uniform -> scalar loads
    size_t wrow = (size_t)blockIdx.x * 128 + (size_t)w * 32;

    float4 bufA[8], bufB[8];
#pragma unroll
    for (int r = 0; r < 8; ++r)
        bufA[r] = *(const float4*)(emb + (wrow + r) * DIM + l * 4);

    for (int tile = 0; tile < 4; ++tile) {
        size_t trow = wrow + (size_t)tile * 8;
        size_t ntrow = wrow + (size_t)((tile < 3) ? tile + 1 : 3) * 8;
        float acc[8][PICK];
#pragma unroll
        for (int r = 0; r < 8; ++r)
#pragma unroll
            for (int j = 0; j < PICK; ++j) acc[r][j] = 0.f;

        CHUNK8(bufA, bufB, 0, trow, 1);
        CHUNK8(bufB, bufA, 1, trow, 2);
        CHUNK8(bufA, bufB, 2, trow, 3);
        CHUNK8(bufB, bufA, 3, ntrow, 0);

        EPI8(&maxv[trow]);
    }
}

__global__ void __launch_bounds__(256)
pass2_kernel(const float* __restrict__ emb, const float* __restrict__ Rt,
             const float* __restrict__ c1, float* __restrict__ out) {
    __shared__ __align__(16) float sMt[PICK * DIM];        // 48 KB
    __shared__ float pooled[128];
    int t = threadIdx.x;
    for (int i = t; i < PICK * DIM / 4; i += 256)
        ((float4*)sMt)[i] = ((const float4*)Rt)[i];
    __syncthreads();

    int l = t & 63, w = t >> 6;
    float cb[PICK];
#pragma unroll
    for (int j = 0; j < PICK; ++j) cb[j] = c1[j];
    size_t bbase = (size_t)blockIdx.x * 128;
    size_t wrow = bbase + (size_t)w * 32;

    float4 bufA[8], bufB[8];
#pragma unroll
    for (int r = 0; r < 8; ++r)
        bufA[r] = *(const float4*)(emb + (wrow + r) * DIM + l * 4);

    for (int tile = 0; tile < 4; ++tile) {
        size_t trow = wrow + (size_t)tile * 8;
        size_t ntrow = wrow + (size_t)((tile < 3) ? tile + 1 : 3) * 8;
        float acc[8][PICK];
#pragma unroll
        for (int r = 0; r < 8; ++r)
#pragma unroll
            for (int j = 0; j < PICK; ++j) acc[r][j] = 0.f;

        CHUNK8(bufA, bufB, 0, trow, 1);
        CHUNK8(bufB, bufA, 1, trow, 2);
        CHUNK8(bufA, bufB, 2, trow, 3);
        CHUNK8(bufB, bufA, 3, ntrow, 0);

        EPI8(&pooled[w * 32 + tile * 8]);
    }
    __syncthreads();

    // phase B: thread t owns cols t*4..t*4+3; wave reads are 1 KB contiguous.
    // Re-walk the block's 128 rows (L3-hot from phase A).
    const float* tp = emb + bbase * DIM + t * 4;
    float4 o = {0.f, 0.f, 0.f, 0.f};
#pragma unroll 8
    for (int r = 0; r < 128; ++r) {
        float pv = pooled[r];
        float4 v = *(const float4*)(tp + (size_t)r * DIM);
        o.x += pv * v.x; o.y += pv * v.y; o.z += pv * v.z; o.w += pv * v.w;
    }
    atomicAdd(&out[t * 4 + 0], o.x);
    atomicAdd(&out[t * 4 + 1], o.y);
    atomicAdd(&out[t * 4 + 2], o.z);
    atomicAdd(&out[t * 4 + 3], o.w);
}

// local top-12 of each 1024-chunk of maxv, single wave, register-resident,
// barrier-free: element q*64+t is only ever scanned AND cleared by lane t.
__global__ void __launch_bounds__(64)
top12_local(const float* __restrict__ maxv, float* __restrict__ cand_v,
            int* __restrict__ cand_i) {
    int t = threadIdx.x;
    int base = blockIdx.x * 1024;
    float lv[16];
#pragma unroll
    for (int q = 0; q < 16; ++q) lv[q] = maxv[base + q * 64 + t];
    for (int k = 0; k < PICK; ++k) {
        float bv = -3e38f; int bi = 0x7fffffff;
#pragma unroll
        for (int q = 0; q < 16; ++q) {
            int ii = base + q * 64 + t;
            float v = lv[q];
            if (v > bv || (v == bv && ii < bi)) { bv = v; bi = ii; }
        }
#pragma unroll
        for (int sft = 1; sft < 64; sft <<= 1) {
            float ov = __shfl_xor(bv, sft, 64);
            int oi = __shfl_xor(bi, sft, 64);
            if (ov > bv || (ov == bv && oi < bi)) { bv = ov; bi = oi; }
        }
        if (t == 0) {
            cand_v[blockIdx.x * PICK + k] = bv;
            cand_i[blockIdx.x * PICK + k] = bi;
        }
#pragma unroll
        for (int q = 0; q < 16; ++q)
            if (base + q * 64 + t == bi) lv[q] = -3e38f;
    }
}

// merge 768 candidates -> global top-12 indices; single wave, 12 regs/lane.
__global__ void __launch_bounds__(64)
top12_merge(const float* __restrict__ cand_v, const int* __restrict__ cand_i,
            int* __restrict__ top_idx) {
    int t = threadIdx.x;
    float lv[12]; int li[12];
#pragma unroll
    for (int q = 0; q < 12; ++q) {
        lv[q] = cand_v[q * 64 + t];
        li[q] = cand_i[q * 64 + t];
    }
    for (int k = 0; k < PICK; ++k) {
        float bv = -3e38f; int bi = 0x7fffffff; int bs = -1;
#pragma unroll
        for (int q = 0; q < 12; ++q) {
            if (lv[q] > bv || (lv[q] == bv && li[q] < bi)) {
                bv = lv[q]; bi = li[q]; bs = q * 64 + t;
            }
        }
#pragma unroll
        for (int sft = 1; sft < 64; sft <<= 1) {
            float ov = __shfl_xor(bv, sft, 64);
            int oi = __shfl_xor(bi, sft, 64);
            int os = __shfl_xor(bs, sft, 64);
            if (ov > bv || (ov == bv && oi < bi)) { bv = ov; bi = oi; bs = os; }
        }
        if (t == 0) top_idx[k] = bi;
#pragma unroll
        for (int q = 0; q < 12; ++q)
            if (q * 64 + t == bs) lv[q] = -3e38f;
    }
}

extern "C" void kernel_launch(void* const* d_in, const int* in_sizes, int n_in,
                              void* d_out, int out_size, void* d_ws, size_t ws_size,
                              hipStream_t stream) {
    const float* emb = (const float*)d_in[0];
    const float* Wq  = (const float*)d_in[1];
    const float* bq  = (const float*)d_in[2];
    const float* Wk  = (const float*)d_in[3];
    const float* bk  = (const float*)d_in[4];
    const int* indices = (const int*)d_in[5];
    float* out = (float*)d_out;
    float* ws = (float*)d_ws;

    float* NK      = ws;             // 12288
    float* Qr      = ws + 12288;     // 12288
    float* Mt      = ws + 24576;     // 12288 (zeroed by rows12 #1)
    float* Rt      = ws + 36864;     // 12288 (zeroed by rows12 #1)
    float* c0      = ws + 49152;     // 16    (zeroed by rows12 #1)
    float* c1      = ws + 49168;     // 16    (zeroed by rows12 #1)
    float* cand_v  = ws + 49184;     // 768
    int*   cand_i  = (int*)(ws + 49952);   // 768
    int*   top_idx = (int*)(ws + 50720);   // 16
    float* maxv    = ws + 50736;     // 65536

    // rows12 #1 also zeros Mt/Rt/c0/c1 (24608 floats at ws+24576) and out.
    rows12_kernel<<<1024, 256, 0, stream>>>(emb, Wk, bk, indices, NK, Mt, out);
    colmat_kernel<<<129, 256, 0, stream>>>(Wq, NK, bq, Mt, c0);
    pass1_kernel<<<512, 256, 0, stream>>>(emb, Mt, c0, maxv);
    top12_local<<<64, 64, 0, stream>>>(maxv, cand_v, cand_i);
    top12_merge<<<1, 64, 0, stream>>>(cand_v, cand_i, top_idx);
    rows12_kernel<<<1024, 256, 0, stream>>>(emb, Wq, bq, top_idx, Qr, nullptr, nullptr);
    colmat_kernel<<<129, 256, 0, stream>>>(Wk, Qr, bk, Rt, c1);
    pass2_kernel<<<512, 256, 0, stream>>>(emb, Rt, c1, out);
}